// Round 11
// baseline (52322.266 us; speedup 1.0000x reference)
//
#include <hip/hip_runtime.h>
#include <math.h>

typedef short s8v __attribute__((ext_vector_type(8)));
typedef float f32x4 __attribute__((ext_vector_type(4)));

// ---------- helpers ----------
__device__ inline float sigm(float x) { return 1.0f / (1.0f + expf(-x)); }
__device__ inline float dot4(const float4 a, const float4 b) {
  return a.x*b.x + a.y*b.y + a.z*b.z + a.w*b.w;
}
__device__ inline float wsum(float v) {
#pragma unroll
  for (int o = 32; o > 0; o >>= 1) v += __shfl_xor(v, o, 64);
  return v;
}
__device__ inline short f2bf(float f) {
  unsigned int u = __float_as_uint(f);
  unsigned int r = u + 0x7FFFu + ((u >> 16) & 1u);
  return (short)(r >> 16);
}
__device__ inline float bf2f(short h) {
  return __uint_as_float(((unsigned int)(unsigned short)h) << 16);
}
__device__ inline void storesplit(float v, short* __restrict__ hi,
                                  short* __restrict__ lo, size_t idx) {
  short h = f2bf(v);
  hi[idx] = h;
  lo[idx] = f2bf(v - bf2f(h));
}

// wave GEMM single-bf16 (global A,B): C[64m x 16n]
template<int LD, int KS>
__device__ __forceinline__ void gemm4(const short* __restrict__ A,
                                      const short* __restrict__ B,
                                      f32x4 acc[4], int lane) {
  int off = (lane & 15) * LD + ((lane >> 4) * 8);
#pragma unroll 4
  for (int kb = 0; kb < KS; kb++) {
    int ko = off + kb*32;
    s8v bb = *(const s8v*)(B + ko);
#pragma unroll
    for (int m = 0; m < 4; m++) {
      s8v aa = *(const s8v*)(A + ko + m*16*LD);
      acc[m] = __builtin_amdgcn_mfma_f32_16x16x32_bf16(aa, bb, acc[m], 0,0,0);
    }
  }
}

// ---------- weight prep ----------
// gates W interleaved: new row r = jt*64 + ul*4 + gi  <->  old row gi*1024 + jt*16 + ul
__global__ void kprep_g(const float* __restrict__ Wih, const float* __restrict__ Whh,
                        short* __restrict__ WgH, short* __restrict__ WgL) {
  int r = blockIdx.y, k = blockIdx.x*256 + threadIdx.x;
  if (k < 1792) {
    int jt = r >> 6, rr = r & 63, ul = rr >> 2, gi = rr & 3;
    int orow = gi*1024 + jt*16 + ul;
    float v = (k < 768) ? Wih[(size_t)orow*768 + k] : Whh[(size_t)orow*1024 + (k-768)];
    storesplit(v, WgH, WgL, (size_t)r*1792 + k);
  }
}
__global__ void kprep_p(const float* __restrict__ Wp, short* __restrict__ W) {
  int j = blockIdx.y, k = blockIdx.x*256 + threadIdx.x;
  W[(size_t)j*1280 + k] = f2bf(Wp[(size_t)j*1280 + k]);
}
__global__ void kprep_q(const float* __restrict__ aw, short* __restrict__ WH,
                        short* __restrict__ WL) {
  int i = blockIdx.x*64 + threadIdx.x;
  storesplit(aw[i], WH, WL, i);
}

// ---------- prologue: xin(t=0) into buffer 0 ----------
__global__ __launch_bounds__(256) void k_prep0(
    const float* __restrict__ x_emb, const float* __restrict__ in_g,
    const float* __restrict__ in_b, short* __restrict__ inbH,
    short* __restrict__ inbL)
{
  __shared__ float rs[4], rq[4];
  int b = blockIdx.x, tid = threadIdx.x, lane = tid & 63, wid = tid >> 6;
  float v3[3]; float s = 0.f, sq = 0.f;
#pragma unroll
  for (int i = 0; i < 3; i++) {
    int k = tid + i * 256;
    float v = (k < 512) ? x_emb[(size_t)b * 256 * 512 + k] : 0.f;
    v3[i] = v; s += v; sq += v * v;
  }
  s = wsum(s); sq = wsum(sq);
  if (lane == 0) { rs[wid] = s; rq[wid] = sq; }
  __syncthreads();
  float ts = rs[0]+rs[1]+rs[2]+rs[3], tq = rq[0]+rq[1]+rq[2]+rq[3];
  float mu = ts / 768.f, var = tq / 768.f - mu * mu;
  float rstd = rsqrtf(var + 1e-5f);
#pragma unroll
  for (int i = 0; i < 3; i++) {
    int k = tid + i * 256;
    storesplit((v3[i] - mu) * rstd * in_g[k] + in_b[k], inbH, inbL, b*1792 + k);
  }
}

// ---------- prologue: qkv(t=0) = bias (mem=0) ----------
__global__ __launch_bounds__(256) void k_prepq0(
    const float* __restrict__ attn_b, float* __restrict__ qkv)
{
  int b = blockIdx.x, tid = threadIdx.x;
  for (int i = tid; i < 24576; i += 256) {
    int ch = i >> 13, j = i & 63;
    qkv[(size_t)b*24576 + i] = attn_b[ch*64 + j];
  }
}

// ---------- kA: gates+cell (64) | attn mt-pairs (128) | logits(t-1) (8) ----------
__global__ __launch_bounds__(512) void kA(
    const short* __restrict__ inbH, const short* __restrict__ inbL,
    short* __restrict__ inbHn, short* __restrict__ inbLn,
    const short* __restrict__ WgH, const short* __restrict__ WgL,
    const float* __restrict__ b_ih, const float* __restrict__ b_hh,
    float* __restrict__ cbuf, float* __restrict__ hbuf,
    float* __restrict__ hstat,
    const float* __restrict__ qkv, float* __restrict__ mem,
    const float* __restrict__ attn_ow, const float* __restrict__ attn_ob,
    const float* __restrict__ l1w, const float* __restrict__ l1b,
    const float* __restrict__ l2w, const float* __restrict__ l2b,
    const float* __restrict__ tn1g, const float* __restrict__ tn1b,
    const float* __restrict__ tn2g, const float* __restrict__ tn2b,
    const short* __restrict__ pob16, const short* __restrict__ Wp16,
    const float* __restrict__ b_proj, float* __restrict__ outs, int t)
{
  __shared__ float pool[35200];
  int bid = blockIdx.x, tid = threadIdx.x;
  int lane = tid & 63;
  if (bid < 64) {
    // ===== gates tile jt, 2-way internal K-split, double-buffered, + cell =====
    if (t >= 256) return;
    int jt = bid;
    int kt = tid >> 8;            // group 0/1
    int tl = tid & 255;
    int w4 = (tid >> 6) & 3;      // wave in group
    short (*sT)[4][2560] = (short(*)[4][2560])((char*)pool + kt*40960);
    int k0 = kt * 896;
    int srow = tl >> 2, scol = (tl & 3) * 8;
    const short* gAH = inbH + srow*1792 + k0 + scol;
    const short* gAL = inbL + srow*1792 + k0 + scol;
    const short* gBH = WgH + (size_t)(jt*64 + srow)*1792 + k0 + scol;
    const short* gBL = WgL + (size_t)(jt*64 + srow)*1792 + k0 + scol;
    int4 rAH = *(const int4*)gAH, rAL = *(const int4*)gAL;
    int4 rBH = *(const int4*)gBH, rBL = *(const int4*)gBL;
    *(int4*)&sT[0][0][srow*40 + scol] = rAH;
    *(int4*)&sT[0][1][srow*40 + scol] = rAL;
    *(int4*)&sT[0][2][srow*40 + scol] = rBH;
    *(int4*)&sT[0][3][srow*40 + scol] = rBL;
    f32x4 acc[4] = {};
    int arow = lane & 15, akk = (lane >> 4) * 8;
    for (int c = 0; c < 28; ++c) {
      int cur = c & 1;
      if (c < 27) {
        rAH = *(const int4*)(gAH + (c+1)*32);
        rAL = *(const int4*)(gAL + (c+1)*32);
        rBH = *(const int4*)(gBH + (c+1)*32);
        rBL = *(const int4*)(gBL + (c+1)*32);
      }
      __syncthreads();
      s8v bh = *(const s8v*)&sT[cur][2][(w4*16 + arow)*40 + akk];
      s8v bl = *(const s8v*)&sT[cur][3][(w4*16 + arow)*40 + akk];
#pragma unroll
      for (int ms = 0; ms < 4; ++ms) {
        s8v ah = *(const s8v*)&sT[cur][0][(arow + ms*16)*40 + akk];
        s8v al = *(const s8v*)&sT[cur][1][(arow + ms*16)*40 + akk];
        acc[ms] = __builtin_amdgcn_mfma_f32_16x16x32_bf16(ah, bh, acc[ms], 0,0,0);
        acc[ms] = __builtin_amdgcn_mfma_f32_16x16x32_bf16(al, bh, acc[ms], 0,0,0);
        acc[ms] = __builtin_amdgcn_mfma_f32_16x16x32_bf16(ah, bl, acc[ms], 0,0,0);
      }
      if (c < 27) {
        *(int4*)&sT[cur^1][0][srow*40 + scol] = rAH;
        *(int4*)&sT[cur^1][1][srow*40 + scol] = rAL;
        *(int4*)&sT[cur^1][2][srow*40 + scol] = rBH;
        *(int4*)&sT[cur^1][3][srow*40 + scol] = rBL;
      }
    }
    __syncthreads();
    // partials -> LDS (sC0 | sC1), then cell
    float* sC = pool;                   // 2 x 64*68 floats
    float* sRed = pool + 8704;          // 1024 floats
    {
      float* sCk = sC + kt*4352;
      int rr = w4*16 + (lane & 15);
#pragma unroll
      for (int ms = 0; ms < 4; ms++)
#pragma unroll
        for (int r = 0; r < 4; r++) {
          int b = ms*16 + (lane>>4)*4 + r;
          sCk[b*68 + rr] = acc[ms][r];
        }
    }
    __syncthreads();
    {
      int b = tid & 63, ug = tid >> 6;
      float sh = 0.f, sh2 = 0.f;
#pragma unroll
      for (int q = 0; q < 2; q++) {
        int ul = ug*2 + q;
        int u = jt*16 + ul;
        float gi_ = sC[b*68 + ul*4 + 0] + sC[4352 + b*68 + ul*4 + 0] + b_ih[u]        + b_hh[u];
        float gf  = sC[b*68 + ul*4 + 1] + sC[4352 + b*68 + ul*4 + 1] + b_ih[1024 + u] + b_hh[1024 + u];
        float gg  = sC[b*68 + ul*4 + 2] + sC[4352 + b*68 + ul*4 + 2] + b_ih[2048 + u] + b_hh[2048 + u];
        float go  = sC[b*68 + ul*4 + 3] + sC[4352 + b*68 + ul*4 + 3] + b_ih[3072 + u] + b_hh[3072 + u];
        float cn = sigm(gf)*cbuf[b*1024 + u] + sigm(gi_)*tanhf(gg);
        float hh = sigm(go)*tanhf(cn);
        cbuf[b*1024 + u] = cn;
        hbuf[b*1024 + u] = hh;
        storesplit(hh, inbHn, inbLn, b*1792 + 768 + u);
        sh += hh; sh2 += hh*hh;
      }
      sRed[ug*64 + b] = sh;
      sRed[512 + ug*64 + b] = sh2;
    }
    __syncthreads();
    if (tid < 64) {
      float s0 = 0.f, s1 = 0.f;
#pragma unroll
      for (int p = 0; p < 8; p++) { s0 += sRed[p*64 + tid]; s1 += sRed[512 + p*64 + tid]; }
      hstat[(tid*64 + jt)*2]     = s0;
      hstat[(tid*64 + jt)*2 + 1] = s1;
    }
  } else if (bid < 192) {
    // ===== attention, mt-pair per block, 512 threads =====
    if (t >= 256) return;
    float* sK  = pool;           // 8704
    float* sV  = pool + 8704;    // 8704
    float* sX  = pool + 17408;   // 2176
    float* sM  = pool + 19584;   // 2176
    float* sO  = pool + 21760;   // 2176
    float* sS  = pool + 23936;   // 10240
    float* sRed= pool + 34176;   // 1024
    int pb = bid - 64;
    int b = pb & 63, pr = pb >> 6;
    int wid = tid >> 6;
    const float* qb = qkv + (size_t)b*3*8192;
    for (int it = 0; it < 2; ++it) {
      int m0 = (pr*2 + it) * 32;
      for (int i = tid*4; i < 8192; i += 2048) {
        *(float4*)&sK[i] = *(const float4*)&qb[8192 + i];
        *(float4*)&sV[i] = *(const float4*)&qb[16384 + i];
      }
      {
        int i = tid*4;
        int m = i >> 6, s = i & 63;
        *(float4*)&sX[m*68+s] = *(const float4*)&qb[m0*64 + i];
        *(float4*)&sM[m*68+s] = *(const float4*)&mem[(size_t)b*8192 + m0*64 + i];
      }
      __syncthreads();
      int m = tid >> 4, hd = (tid >> 2) & 3, q = tid & 3;
      const float* qp = sX + m*68 + hd*16;
      float4 q0 = *(const float4*)(qp),   q1 = *(const float4*)(qp+4);
      float4 q2 = *(const float4*)(qp+8), q3 = *(const float4*)(qp+12);
      int kmb = q * 32;
      float mx = -1e30f;
#pragma unroll 4
      for (int kk = 0; kk < 32; kk++) {
        const float* kp = sK + (kmb+kk)*64 + hd*16;
        float sc = dot4(q0, *(const float4*)kp)     + dot4(q1, *(const float4*)(kp+4))
                 + dot4(q2, *(const float4*)(kp+8)) + dot4(q3, *(const float4*)(kp+12));
        mx = fmaxf(mx, sc * 0.25f);
      }
      float4 o0 = {0,0,0,0}, o1 = {0,0,0,0}, o2 = {0,0,0,0}, o3 = {0,0,0,0};
      float sum = 0.f;
#pragma unroll 4
      for (int kk = 0; kk < 32; kk++) {
        const float* kp = sK + (kmb+kk)*64 + hd*16;
        float sc = dot4(q0, *(const float4*)kp)     + dot4(q1, *(const float4*)(kp+4))
                 + dot4(q2, *(const float4*)(kp+8)) + dot4(q3, *(const float4*)(kp+12));
        float e = expf(sc * 0.25f - mx);
        sum += e;
        const float* vp = sV + (kmb+kk)*64 + hd*16;
        float4 v0 = *(const float4*)vp,     v1 = *(const float4*)(vp+4);
        float4 v2 = *(const float4*)(vp+8), v3 = *(const float4*)(vp+12);
        o0.x += e*v0.x; o0.y += e*v0.y; o0.z += e*v0.z; o0.w += e*v0.w;
        o1.x += e*v1.x; o1.y += e*v1.y; o1.z += e*v1.z; o1.w += e*v1.w;
        o2.x += e*v2.x; o2.y += e*v2.y; o2.z += e*v2.z; o2.w += e*v2.w;
        o3.x += e*v3.x; o3.y += e*v3.y; o3.z += e*v3.z; o3.w += e*v3.w;
      }
      {
        float* pp = sS + tid*20;
        *(float4*)&pp[0]  = o0; *(float4*)&pp[4]  = o1;
        *(float4*)&pp[8]  = o2; *(float4*)&pp[12] = o3;
        sRed[tid] = mx; sRed[512+tid] = sum;
      }
      __syncthreads();
      if (q == 0) {
        float m1 = sRed[tid+1], m2 = sRed[tid+2], m3 = sRed[tid+3];
        float M = fmaxf(fmaxf(mx, m1), fmaxf(m2, m3));
        float e0 = expf(mx - M), e1 = expf(m1 - M), e2 = expf(m2 - M), e3 = expf(m3 - M);
        float inv = 1.0f / (sum*e0 + sRed[512+tid+1]*e1 + sRed[512+tid+2]*e2
                            + sRed[512+tid+3]*e3);
        const float* p1 = sS + (tid+1)*20;
        const float* p2 = sS + (tid+2)*20;
        const float* p3 = sS + (tid+3)*20;
        float oo[16];
        *(float4*)&oo[0] = o0; *(float4*)&oo[4] = o1;
        *(float4*)&oo[8] = o2; *(float4*)&oo[12] = o3;
        float* op = sO + m*68 + hd*16;
#pragma unroll
        for (int d = 0; d < 16; d++)
          op[d] = (oo[d]*e0 + p1[d]*e1 + p2[d]*e2 + p3[d]*e3) * inv;
      }
      __syncthreads();
      for (int idx = tid; idx < 4096; idx += 512) {
        int j = idx >> 6, s = idx & 63;
        sS[j*68 + s] = attn_ow[idx];
      }
      __syncthreads();
      {
        int mm = tid >> 4, jset = tid & 15;
        float4 orow[16];
#pragma unroll
        for (int r = 0; r < 16; r++) orow[r] = *(const float4*)&sO[mm*68 + r*4];
#pragma unroll
        for (int i = 0; i < 4; i++) {
          int j = jset + 16*i;
          const float* wr = sS + j*68;
          float acc = attn_ob[j];
#pragma unroll
          for (int r = 0; r < 16; r++) acc += dot4(orow[r], *(const float4*)&wr[r*4]);
          sM[mm*68 + j] += acc;
        }
      }
      __syncthreads();
      for (int r = wid; r < 32; r += 8) {
        float v = sM[r*68 + lane];
        float ssum = wsum(v), ssq = wsum(v*v);
        float mu = ssum*(1.f/64), var = ssq*(1.f/64) - mu*mu;
        sX[r*68+lane] = (v - mu)*rsqrtf(var+1e-5f)*tn1g[lane] + tn1b[lane];
      }
      for (int idx = tid; idx < 8192; idx += 512) {
        int f = idx >> 6, s = idx & 63;
        sK[f*68 + s] = l1w[idx];
      }
      for (int idx = tid; idx < 8192; idx += 512) {
        int j = idx >> 7, s = idx & 127;
        sV[j*132 + s] = l2w[idx];
      }
      __syncthreads();
      {
        int mm = tid >> 4, fs = tid & 15;
        float4 xr[16];
#pragma unroll
        for (int r = 0; r < 16; r++) xr[r] = *(const float4*)&sX[mm*68 + r*4];
#pragma unroll 4
        for (int i = 0; i < 8; i++) {
          int f = fs + 16*i;
          const float* wr = sK + f*68;
          float acc = l1b[f];
#pragma unroll
          for (int r = 0; r < 16; r++) acc += dot4(xr[r], *(const float4*)&wr[r*4]);
          sS[mm*132 + f] = 0.5f*acc*(1.0f + erff(acc*0.70710678118654752f));
        }
      }
      __syncthreads();
      {
        int mm = tid >> 4, jset = tid & 15;
        float acc6[4];
#pragma unroll
        for (int i = 0; i < 4; i++) acc6[i] = sX[mm*68 + jset + 16*i] + l2b[jset + 16*i];
#pragma unroll
        for (int h = 0; h < 2; h++) {
          float4 fr[16];
#pragma unroll
          for (int r = 0; r < 16; r++) fr[r] = *(const float4*)&sS[mm*132 + h*64 + r*4];
#pragma unroll
          for (int i = 0; i < 4; i++) {
            int j = jset + 16*i;
            const float* wr = sV + j*132 + h*64;
            float a = 0.f;
#pragma unroll
            for (int r = 0; r < 16; r++) a += dot4(fr[r], *(const float4*)&wr[r*4]);
            acc6[i] += a;
          }
        }
#pragma unroll
        for (int i = 0; i < 4; i++) sO[mm*68 + jset + 16*i] = acc6[i];
      }
      __syncthreads();
      for (int r = wid; r < 32; r += 8) {
        float v = sO[r*68 + lane];
        float ssum = wsum(v), ssq = wsum(v*v);
        float mu = ssum*(1.f/64), var = ssq*(1.f/64) - mu*mu;
        mem[(size_t)b*8192 + (m0+r)*64 + lane] =
            (v - mu)*rsqrtf(var+1e-5f)*tn2g[lane] + tn2b[lane];
      }
      __syncthreads();
    }
  } else {
    // ===== logits(t-1): 8 blocks x 8 waves x 16n =====
    if (t == 0) return;
    int jt = bid - 192;
    int w = tid >> 6;
    f32x4 acc[4] = {};
    const short* B = Wp16 + (size_t)(jt*128 + w*16) * 1280;
    gemm4<1280, 40>(pob16, B, acc, lane);
    int j = jt*128 + w*16 + (lane & 15);
    float bv = b_proj[j];
#pragma unroll
    for (int ms = 0; ms < 4; ms++)
#pragma unroll
      for (int r = 0; r < 4; r++) {
        int b = ms*16 + (lane>>4)*4 + r;
        outs[((size_t)b*256 + (t-1))*1024 + j] = acc[ms][r] + bv;
      }
  }
}

// ---------- kC: heads GEMV + addressing + qkv(t+1) + pob + xin ----------
__global__ __launch_bounds__(512) void kC(
    float* __restrict__ mem, const float* __restrict__ hstat,
    const float* __restrict__ hbuf,
    const float* __restrict__ cn_g, const float* __restrict__ cn_b,
    const float* __restrict__ W_rk, const float* __restrict__ W_wk,
    const float* __restrict__ W_ev, const float* __restrict__ W_ws,
    const float* __restrict__ b_rk, const float* __restrict__ b_wk,
    const float* __restrict__ b_ev, const float* __restrict__ b_ws,
    const float* __restrict__ rkn_g, const float* __restrict__ rkn_b,
    const float* __restrict__ wkn_g, const float* __restrict__ wkn_b,
    const float* __restrict__ mng, const float* __restrict__ mnb,
    const float* __restrict__ pog, const float* __restrict__ pob,
    const float* __restrict__ x_emb, const float* __restrict__ in_g,
    const float* __restrict__ in_b,
    const short* __restrict__ WqH, const short* __restrict__ WqL,
    const float* __restrict__ attn_b,
    float* __restrict__ qkv,
    short* __restrict__ inbHn, short* __restrict__ inbLn,
    short* __restrict__ pob16, int tnext)
{
  __shared__ float P[20960];
  float* sMT  = P;            // 8192
  float* sMN  = P + 8192;     // 8320 (later sAH/sAL)
  float* sHn  = P + 16512;    // 1024
  float* sHOut= P + 17536;    // 832
  float* sRk  = P + 18368;    // 256
  float* sWk  = P + 18624;    // 256
  float* sEv  = P + 18880;    // 256
  float* sWs  = P + 19136;    // 4
  float* sRw  = P + 19140;    // 512
  float* sWw  = P + 19652;    // 512
  float* sRc  = P + 20164;    // 256
  float* sRcP = P + 20420;    // 512
  float* rs   = P + 20932;    // 8
  float* rq   = P + 20940;    // 8
  float* sHst = P + 20948;    // 2
  int b = blockIdx.x, tid = threadIdx.x, lane = tid & 63, wv = tid >> 6;
  // 1: stage mem + hn stats
  for (int i = tid*4; i < 8192; i += 2048)
    *(float4*)&sMT[i] = *(const float4*)&mem[(size_t)b*8192 + i];
  if (wv == 0) {
    float v0 = hstat[(b*64 + lane)*2], v1 = hstat[(b*64 + lane)*2 + 1];
    float s0 = wsum(v0), s1 = wsum(v1);
    if (lane == 0) {
      float mu = s0 / 1024.f;
      sHst[0] = mu;
      sHst[1] = rsqrtf(s1/1024.f - mu*mu + 1e-5f);
    }
  }
  __syncthreads();
  // 2: hn + mem_n LN
  {
    float mu = sHst[0], rstd = sHst[1];
    for (int u = tid; u < 1024; u += 512)
      sHn[u] = (hbuf[b*1024 + u] - mu)*rstd*cn_g[u] + cn_b[u];
  }
  for (int r = wv; r < 128; r += 8) {
    float v = sMT[r*64 + lane];
    float ssum = wsum(v), ssq = wsum(v*v);
    float mu = ssum*(1.f/64), var = ssq*(1.f/64) - mu*mu;
    sMN[r*65 + lane] = (v - mu)*rsqrtf(var+1e-5f)*mng[lane] + mnb[lane];
  }
  __syncthreads();
  // 3: heads GEMV (fp32, wave per row)
  for (int r = wv; r < 772; r += 8) {
    const float* wr;
    if (r < 256)      wr = W_rk + (size_t)r*1024;
    else if (r < 512) wr = W_wk + (size_t)(r-256)*1024;
    else if (r < 768) wr = W_ev + (size_t)(r-512)*1024;
    else              wr = W_ws + (size_t)(r-768)*1024;
    float acc = 0.f;
#pragma unroll
    for (int i = 0; i < 16; i++) acc += wr[lane + 64*i] * sHn[lane + 64*i];
    acc = wsum(acc);
    if (lane == 0) sHOut[r] = acc;
  }
  __syncthreads();
  // 4: key LN / sigmoids
  if (wv < 4) {
    float v = sHOut[wv*64 + lane] + b_rk[wv*64 + lane];
    float ssum = wsum(v), ssq = wsum(v*v);
    float mu = ssum*(1.f/64), var = ssq*(1.f/64) - mu*mu;
    sRk[wv*64 + lane] = (v - mu)*rsqrtf(var+1e-5f)*rkn_g[lane] + rkn_b[lane];
  } else {
    int n = wv - 4;
    float v = sHOut[256 + n*64 + lane] + b_wk[n*64 + lane];
    float ssum = wsum(v), ssq = wsum(v*v);
    float mu = ssum*(1.f/64), var = ssq*(1.f/64) - mu*mu;
    sWk[n*64 + lane] = (v - mu)*rsqrtf(var+1e-5f)*wkn_g[lane] + wkn_b[lane];
  }
  if (tid < 256) sEv[tid] = sigm(sHOut[512 + tid] + b_ev[tid]);
  if (tid >= 256 && tid < 260) sWs[tid-256] = sigm(sHOut[768 + (tid-256)] + b_ws[tid-256]);
  __syncthreads();
  // 5: scores
#pragma unroll
  for (int q = 0; q < 2; q++) {
    int idx = tid + q*512;
    int which = idx >> 9;
    int n = (idx >> 7) & 3, m = idx & 127;
    const float* key = (which ? sWk : sRk) + n*64;
    const float* mr = sMN + m*65;
    float acc = 0.f;
#pragma unroll 8
    for (int k = 0; k < 64; k++) acc += key[k]*mr[k];
    (which ? sWw : sRw)[n*128 + m] = acc;
  }
  __syncthreads();
  // 6: softmax (8 rows, one per wave)
  {
    float* row = (wv < 4) ? (sRw + wv*128) : (sWw + (wv-4)*128);
    float a0 = row[lane], a1 = row[lane+64];
    float mx = fmaxf(a0, a1);
#pragma unroll
    for (int o = 32; o > 0; o >>= 1) mx = fmaxf(mx, __shfl_xor(mx, o, 64));
    float e0 = expf(a0 - mx), e1 = expf(a1 - mx);
    float inv = 1.0f / wsum(e0 + e1);
    row[lane] = e0*inv; row[lane+64] = e1*inv;
  }
  __syncthreads();
  // 7a: rc partials
  {
    int idx = tid & 255, h2 = tid >> 8;
    int n = idx >> 6, s2 = idx & 63;
    float acc = 0.f;
    for (int mm = h2*64; mm < h2*64 + 64; mm++) acc += sRw[n*128 + mm] * sMT[mm*64 + s2];
    sRcP[tid] = acc;
  }
  __syncthreads();
  // 7b: rc combine + mem update (in place, also into sMT)
  if (tid < 256) sRc[tid] = sRcP[tid] + sRcP[256 + tid];
  for (int idx = tid; idx < 8192; idx += 512) {
    int mm = idx >> 6, s2 = idx & 63;
    float er = 0.f, ad = 0.f;
#pragma unroll
    for (int n = 0; n < 4; n++) {
      float w = sWw[n*128 + mm];
      er += w * sEv[n*64 + s2];
      ad += w * sWs[n] * sWk[n*64 + s2];
    }
    float val = sMT[idx]*(1.0f - er) + ad;
    mem[(size_t)b*8192 + idx] = val;
    sMT[idx] = val;
  }
  __syncthreads();
  // 8: mem -> bf16 split into LDS (overlay sMN)
  short* sAH = (short*)(P + 8192);
  short* sAL = sAH + 8192;
  for (int idx = tid; idx < 8192; idx += 512) {
    float v = sMT[idx];
    short h = f2bf(v);
    sAH[idx] = h;
    sAL[idx] = f2bf(v - bf2f(h));
  }
  __syncthreads();
  // 9: qkv(t+1) MFMA: C[128m][192j], K=64, 8 waves x 16 m
  {
    int ao = (wv*16 + (lane & 15))*64 + (lane >> 4)*8;
    s8v ah0 = *(const s8v*)(sAH + ao);
    s8v ah1 = *(const s8v*)(sAH + ao + 32);
    s8v al0 = *(const s8v*)(sAL + ao);
    s8v al1 = *(const s8v*)(sAL + ao + 32);
    int bo = (lane & 15)*64 + (lane >> 4)*8;
    for (int n = 0; n < 12; n++) {
      s8v bh0 = *(const s8v*)(WqH + bo + n*1024);
      s8v bh1 = *(const s8v*)(WqH + bo + n*1024 + 32);
      s8v bl0 = *(const s8v*)(WqL + bo + n*1024);
      s8v bl1 = *(const s8v*)(WqL + bo + n*1024 + 32);
      f32x4 acc = {};
      acc = __builtin_amdgcn_mfma_f32_16x16x32_bf16(ah0, bh0, acc, 0,0,0);
      acc = __builtin_amdgcn_mfma_f32_16x16x32_bf16(ah1, bh1, acc, 0,0,0);
      acc = __builtin_amdgcn_mfma_f32_16x16x32_bf16(al0, bh0, acc, 0,0,0);
      acc = __builtin_amdgcn_mfma_f32_16x16x32_bf16(al1, bh1, acc, 0,0,0);
      acc = __builtin_amdgcn_mfma_f32_16x16x32_bf16(ah0, bl0, acc, 0,0,0);
      acc = __builtin_amdgcn_mfma_f32_16x16x32_bf16(ah1, bl1, acc, 0,0,0);
      int j = n*16 + (lane & 15);
      int ch = j >> 6, jj = j & 63;
      float bv = attn_b[j];
#pragma unroll
      for (int r = 0; r < 4; r++) {
        int m0 = wv*16 + (lane>>4)*4 + r;
        qkv[((size_t)(b*3 + ch)*128 + m0)*64 + jj] = acc[r] + bv;
      }
    }
  }
  // 10: pob (over [hn | rc])
  {
    float v5[3]; float s = 0.f, sq = 0.f;
#pragma unroll
    for (int i = 0; i < 3; i++) {
      int k = tid + i*512;
      float v = 0.f;
      if (k < 1280) v = (k < 1024) ? sHn[k] : sRc[k-1024];
      v5[i] = v; s += v; sq += v*v;
    }
    s = wsum(s); sq = wsum(sq);
    if (lane == 0) { rs[wv] = s; rq[wv] = sq; }
    __syncthreads();
    float ts = 0.f, tq = 0.f;
#pragma unroll
    for (int p = 0; p < 8; p++) { ts += rs[p]; tq += rq[p]; }
    float mu = ts/1280.f, var = tq/1280.f - mu*mu;
    float rstd = rsqrtf(var + 1e-5f);
#pragma unroll
    for (int i = 0; i < 3; i++) {
      int k = tid + i*512;
      if (k < 1280) pob16[b*1280 + k] = f2bf((v5[i] - mu)*rstd*pog[k] + pob[k]);
    }
  }
  // 11: next-step xin
  if (tnext < 256) {
    __syncthreads();
    float v3[2]; float s2 = 0.f, q2 = 0.f;
#pragma unroll
    for (int i = 0; i < 2; i++) {
      int k = tid + i*512;
      float v = 0.f;
      if (k < 768) v = (k < 512) ? x_emb[((size_t)b*256 + tnext)*512 + k] : sRc[k-512];
      v3[i] = v; s2 += v; q2 += v*v;
    }
    s2 = wsum(s2); q2 = wsum(q2);
    if (lane == 0) { rs[wv] = s2; rq[wv] = q2; }
    __syncthreads();
    float ts = 0.f, tq = 0.f;
#pragma unroll
    for (int p = 0; p < 8; p++) { ts += rs[p]; tq += rq[p]; }
    float mu = ts/768.f, var = tq/768.f - mu*mu;
    float rstd = rsqrtf(var + 1e-5f);
#pragma unroll
    for (int i = 0; i < 2; i++) {
      int k = tid + i*512;
      if (k < 768)
        storesplit((v3[i] - mu)*rstd*in_g[k] + in_b[k], inbHn, inbLn, b*1792 + k);
    }
  }
}

// ---------- final copy ----------
__global__ void k_final(const float* __restrict__ mem, const float* __restrict__ hbuf,
                        const float* __restrict__ cbuf, float* __restrict__ out)
{
  int i = blockIdx.x * 256 + threadIdx.x;
  if (i < 524288) out[16777216 + i] = mem[i];
  if (i < 65536) {
    out[17301504 + i] = hbuf[i];
    out[17367040 + i] = cbuf[i];
  }
}

extern "C" void kernel_launch(void* const* d_in, const int* in_sizes, int n_in,
                              void* d_out, int out_size, void* d_ws, size_t ws_size,
                              hipStream_t stream) {
  const float* x_emb  = (const float*)d_in[0];
  const float* in_g   = (const float*)d_in[1];
  const float* in_b   = (const float*)d_in[2];
  const float* W_ih   = (const float*)d_in[3];
  const float* W_hh   = (const float*)d_in[4];
  const float* b_ih   = (const float*)d_in[5];
  const float* b_hh   = (const float*)d_in[6];
  const float* cn_g   = (const float*)d_in[7];
  const float* cn_b   = (const float*)d_in[8];
  const float* W_rk   = (const float*)d_in[9];
  const float* b_rk   = (const float*)d_in[10];
  const float* W_wk   = (const float*)d_in[11];
  const float* b_wk   = (const float*)d_in[12];
  const float* W_ws   = (const float*)d_in[13];
  const float* b_ws   = (const float*)d_in[14];
  const float* W_ev   = (const float*)d_in[15];
  const float* b_ev   = (const float*)d_in[16];
  const float* attn_w = (const float*)d_in[17];
  const float* attn_b = (const float*)d_in[18];
  const float* attn_ow= (const float*)d_in[19];
  const float* attn_ob= (const float*)d_in[20];
  const float* l1_w   = (const float*)d_in[21];
  const float* l1_b   = (const float*)d_in[22];
  const float* l2_w   = (const float*)d_in[23];
  const float* l2_b   = (const float*)d_in[24];
  const float* tn1_g  = (const float*)d_in[25];
  const float* tn1_b  = (const float*)d_in[26];
  const float* tn2_g  = (const float*)d_in[27];
  const float* tn2_b  = (const float*)d_in[28];
  const float* rkn_g  = (const float*)d_in[29];
  const float* rkn_b  = (const float*)d_in[30];
  const float* wkn_g  = (const float*)d_in[31];
  const float* wkn_b  = (const float*)d_in[32];
  const float* mn_g   = (const float*)d_in[33];
  const float* mn_b   = (const float*)d_in[34];
  const float* po_g   = (const float*)d_in[35];
  const float* po_b   = (const float*)d_in[36];
  const float* W_proj = (const float*)d_in[37];
  const float* b_proj = (const float*)d_in[38];

  float* ws = (float*)d_ws;
  float* mem   = ws;                  // 524288
  float* cbuf  = ws + 524288;         // 65536
  float* hbuf  = ws + 589824;         // 65536
  float* hstat = ws + 655360;         // 8192
  float* qkvb  = ws + 663552;         // 1572864 -> end 2236416 floats
  short* sb    = (short*)(ws + 2236416);
  short* inbH0 = sb;                  // 114688
  short* inbL0 = sb + 114688;
  short* inbH1 = sb + 229376;
  short* inbL1 = sb + 344064;         // -> 458752
  short* pob16 = sb + 458752;         // 81920
  short* WqH   = sb + 540672;         // 12288
  short* WqL   = sb + 552960;         // 12288
  short* WgH   = sb + 565248;         // 7340032
  short* WgL   = sb + 7905280;        // 7340032
  short* Wp16  = sb + 15245312;       // 1310720 -> end 16556032 shorts

  hipMemsetAsync(ws, 0, 655360 * sizeof(float), stream);      // mem, cbuf, hbuf
  hipMemsetAsync(sb, 0, 458752 * sizeof(short), stream);      // inb x2

  kprep_g<<<dim3(7, 4096), 256, 0, stream>>>(W_ih, W_hh, WgH, WgL);
  kprep_p<<<dim3(5, 1024), 256, 0, stream>>>(W_proj, Wp16);
  kprep_q<<<dim3(192), 64, 0, stream>>>(attn_w, WqH, WqL);
  k_prep0<<<64, 256, 0, stream>>>(x_emb, in_g, in_b, inbH0, inbL0);
  k_prepq0<<<64, 256, 0, stream>>>(attn_b, qkvb);

  float* outs = (float*)d_out;
  short* bufsH[2] = {inbH0, inbH1};
  short* bufsL[2] = {inbL0, inbL1};
  for (int t = 0; t < 256; t++) {
    kA<<<200, 512, 0, stream>>>(bufsH[t&1], bufsL[t&1], bufsH[(t+1)&1], bufsL[(t+1)&1],
                                WgH, WgL, b_ih, b_hh, cbuf, hbuf, hstat,
                                qkvb, mem, attn_ow, attn_ob,
                                l1_w, l1_b, l2_w, l2_b,
                                tn1_g, tn1_b, tn2_g, tn2_b,
                                pob16, Wp16, b_proj, outs, t);
    kC<<<64, 512, 0, stream>>>(mem, hstat, hbuf, cn_g, cn_b,
                               W_rk, W_wk, W_ev, W_ws,
                               b_rk, b_wk, b_ev, b_ws,
                               rkn_g, rkn_b, wkn_g, wkn_b,
                               mn_g, mn_b, po_g, po_b,
                               x_emb, in_g, in_b, WqH, WqL, attn_b,
                               qkvb, bufsH[(t+1)&1], bufsL[(t+1)&1], pob16, t+1);
  }
  // last-step logits
  kA<<<200, 512, 0, stream>>>(bufsH[0], bufsL[0], bufsH[1], bufsL[1],
                              WgH, WgL, b_ih, b_hh, cbuf, hbuf, hstat,
                              qkvb, mem, attn_ow, attn_ob,
                              l1_w, l1_b, l2_w, l2_b,
                              tn1_g, tn1_b, tn2_g, tn2_b,
                              pob16, Wp16, b_proj, outs, 256);
  k_final<<<2048, 256, 0, stream>>>(mem, hbuf, cbuf, (float*)d_out);
}

// Round 12
// 25767.081 us; speedup vs baseline: 2.0306x; 2.0306x over previous
//
#include <hip/hip_runtime.h>
#include <math.h>

typedef short s8v __attribute__((ext_vector_type(8)));
typedef float f32x4 __attribute__((ext_vector_type(4)));

// ---------- helpers ----------
__device__ inline float sigm(float x) { return 1.0f / (1.0f + expf(-x)); }
__device__ inline float dot4(const float4 a, const float4 b) {
  return a.x*b.x + a.y*b.y + a.z*b.z + a.w*b.w;
}
__device__ inline float wsum(float v) {
#pragma unroll
  for (int o = 32; o > 0; o >>= 1) v += __shfl_xor(v, o, 64);
  return v;
}
__device__ inline short f2bf(float f) {
  unsigned int u = __float_as_uint(f);
  unsigned int r = u + 0x7FFFu + ((u >> 16) & 1u);
  return (short)(r >> 16);
}
__device__ inline float bf2f(short h) {
  return __uint_as_float(((unsigned int)(unsigned short)h) << 16);
}
__device__ inline void storesplit(float v, short* __restrict__ hi,
                                  short* __restrict__ lo, size_t idx) {
  short h = f2bf(v);
  hi[idx] = h;
  lo[idx] = f2bf(v - bf2f(h));
}

// wave GEMM single-bf16 (global A,B): C[64m x 16n]
template<int LD, int KS>
__device__ __forceinline__ void gemm4(const short* __restrict__ A,
                                      const short* __restrict__ B,
                                      f32x4 acc[4], int lane) {
  int off = (lane & 15) * LD + ((lane >> 4) * 8);
#pragma unroll 4
  for (int kb = 0; kb < KS; kb++) {
    int ko = off + kb*32;
    s8v bb = *(const s8v*)(B + ko);
#pragma unroll
    for (int m = 0; m < 4; m++) {
      s8v aa = *(const s8v*)(A + ko + m*16*LD);
      acc[m] = __builtin_amdgcn_mfma_f32_16x16x32_bf16(aa, bb, acc[m], 0,0,0);
    }
  }
}

// ---------- weight prep ----------
__global__ void kprep_g(const float* __restrict__ Wih, const float* __restrict__ Whh,
                        short* __restrict__ WgH, short* __restrict__ WgL) {
  int r = blockIdx.y, k = blockIdx.x*256 + threadIdx.x;
  if (k < 1792) {
    int jt = r >> 6, rr = r & 63, ul = rr >> 2, gi = rr & 3;
    int orow = gi*1024 + jt*16 + ul;
    float v = (k < 768) ? Wih[(size_t)orow*768 + k] : Whh[(size_t)orow*1024 + (k-768)];
    storesplit(v, WgH, WgL, (size_t)r*1792 + k);
  }
}
__global__ void kprep_p(const float* __restrict__ Wp, short* __restrict__ W) {
  int j = blockIdx.y, k = blockIdx.x*256 + threadIdx.x;
  W[(size_t)j*1280 + k] = f2bf(Wp[(size_t)j*1280 + k]);
}
__global__ void kprep_h(const float* __restrict__ Wrk, const float* __restrict__ Wwk,
                        const float* __restrict__ Wev, const float* __restrict__ Wws,
                        short* __restrict__ WhH, short* __restrict__ WhL) {
  int j = blockIdx.y, k = blockIdx.x*256 + threadIdx.x;
  float v;
  if (j < 256)      v = Wrk[(size_t)j*1024 + k];
  else if (j < 512) v = Wwk[(size_t)(j-256)*1024 + k];
  else if (j < 768) v = Wev[(size_t)(j-512)*1024 + k];
  else if (j < 772) v = Wws[(size_t)(j-768)*1024 + k];
  else v = 0.f;
  storesplit(v, WhH, WhL, (size_t)j*1024 + k);
}
__global__ void kprep_q(const float* __restrict__ aw, short* __restrict__ WH,
                        short* __restrict__ WL) {
  int i = blockIdx.x*64 + threadIdx.x;
  storesplit(aw[i], WH, WL, i);
}

// ---------- prologue: xin for t=0 into buffer 0 ----------
__global__ __launch_bounds__(256) void k_prep0(
    const float* __restrict__ x_emb, const float* __restrict__ in_g,
    const float* __restrict__ in_b, short* __restrict__ inbH,
    short* __restrict__ inbL)
{
  __shared__ float rs[4], rq[4];
  int b = blockIdx.x, tid = threadIdx.x, lane = tid & 63, wid = tid >> 6;
  float v3[3]; float s = 0.f, sq = 0.f;
#pragma unroll
  for (int i = 0; i < 3; i++) {
    int k = tid + i * 256;
    float v = (k < 512) ? x_emb[(size_t)b * 256 * 512 + k] : 0.f;
    v3[i] = v; s += v; sq += v * v;
  }
  s = wsum(s); sq = wsum(sq);
  if (lane == 0) { rs[wid] = s; rq[wid] = sq; }
  __syncthreads();
  float ts = rs[0]+rs[1]+rs[2]+rs[3], tq = rq[0]+rq[1]+rq[2]+rq[3];
  float mu = ts / 768.f, var = tq / 768.f - mu * mu;
  float rstd = rsqrtf(var + 1e-5f);
#pragma unroll
  for (int i = 0; i < 3; i++) {
    int k = tid + i * 256;
    storesplit((v3[i] - mu) * rstd * in_g[k] + in_b[k], inbH, inbL, b*1792 + k);
  }
}

// ---------- kA: gates K-split + cell (128) | qkv (64) | logits(t-1) (16) ----------
__global__ __launch_bounds__(256) void kA(
    const short* __restrict__ inbH, const short* __restrict__ inbL,
    short* __restrict__ inbHn, short* __restrict__ inbLn,
    const short* __restrict__ WgH, const short* __restrict__ WgL,
    const float* __restrict__ b_ih, const float* __restrict__ b_hh,
    float* __restrict__ cbuf, float* __restrict__ hbuf,
    float* __restrict__ hstat, float* __restrict__ gatesP,
    unsigned* __restrict__ tick,
    const short* __restrict__ membH, const short* __restrict__ membL,
    const short* __restrict__ WqH, const short* __restrict__ WqL,
    const float* __restrict__ attn_b,
    const short* __restrict__ pob16, const short* __restrict__ Wp16,
    const float* __restrict__ b_proj,
    float* __restrict__ qkv, float* __restrict__ outs, int t)
{
  __shared__ char poolA[40960];
  __shared__ unsigned sOld;
  int bid = blockIdx.x, tid = threadIdx.x, lane = tid & 63, w = tid >> 6;
  if (bid < 128) {           // gates tile jt, K-half kt*896, + cell by pair-finisher
    if (t >= 256) return;
    short (*sT)[4][2560] = (short(*)[4][2560])poolA;
    int jt = bid & 63, kt = bid >> 6;
    int k0 = kt * 896;
    int srow = tid >> 2, scol = (tid & 3) * 8;
    const short* gAH = inbH + srow*1792 + k0 + scol;
    const short* gAL = inbL + srow*1792 + k0 + scol;
    const short* gBH = WgH + (size_t)(jt*64 + srow)*1792 + k0 + scol;
    const short* gBL = WgL + (size_t)(jt*64 + srow)*1792 + k0 + scol;
    int4 rAH = *(const int4*)gAH, rAL = *(const int4*)gAL;
    int4 rBH = *(const int4*)gBH, rBL = *(const int4*)gBL;
    // prime buffer 0
    *(int4*)&sT[0][0][srow*40 + scol] = rAH;
    *(int4*)&sT[0][1][srow*40 + scol] = rAL;
    *(int4*)&sT[0][2][srow*40 + scol] = rBH;
    *(int4*)&sT[0][3][srow*40 + scol] = rBL;
    f32x4 acc[4] = {};
    int arow = lane & 15, akk = (lane >> 4) * 8;
    for (int c = 0; c < 28; ++c) {
      int cur = c & 1;
      if (c < 27) {
        rAH = *(const int4*)(gAH + (c+1)*32);
        rAL = *(const int4*)(gAL + (c+1)*32);
        rBH = *(const int4*)(gBH + (c+1)*32);
        rBL = *(const int4*)(gBL + (c+1)*32);
      }
      __syncthreads();
      s8v bh = *(const s8v*)&sT[cur][2][(w*16 + arow)*40 + akk];
      s8v bl = *(const s8v*)&sT[cur][3][(w*16 + arow)*40 + akk];
#pragma unroll
      for (int ms = 0; ms < 4; ++ms) {
        s8v ah = *(const s8v*)&sT[cur][0][(arow + ms*16)*40 + akk];
        s8v al = *(const s8v*)&sT[cur][1][(arow + ms*16)*40 + akk];
        acc[ms] = __builtin_amdgcn_mfma_f32_16x16x32_bf16(ah, bh, acc[ms], 0,0,0);
        acc[ms] = __builtin_amdgcn_mfma_f32_16x16x32_bf16(al, bh, acc[ms], 0,0,0);
        acc[ms] = __builtin_amdgcn_mfma_f32_16x16x32_bf16(ah, bl, acc[ms], 0,0,0);
      }
      if (c < 27) {
        *(int4*)&sT[cur^1][0][srow*40 + scol] = rAH;
        *(int4*)&sT[cur^1][1][srow*40 + scol] = rAL;
        *(int4*)&sT[cur^1][2][srow*40 + scol] = rBH;
        *(int4*)&sT[cur^1][3][srow*40 + scol] = rBL;
      }
    }
    // store own partial
    {
      float* gp = gatesP + (size_t)kt * 262144;
      int j = jt*64 + w*16 + (lane & 15);
#pragma unroll
      for (int ms = 0; ms < 4; ms++)
#pragma unroll
        for (int r = 0; r < 4; r++) {
          int b = ms*16 + (lane>>4)*4 + r;
          gp[b*4096 + j] = acc[ms][r];
        }
    }
    __syncthreads();
    if (tid == 0) {
      __threadfence();
      sOld = __hip_atomic_fetch_add(&tick[jt], 1u, __ATOMIC_ACQ_REL,
                                    __HIP_MEMORY_SCOPE_AGENT);
    }
    __syncthreads();
    if (!(sOld & 1u)) return;          // first arriver done
    // finisher: add partner partial (agent-scope loads), then LSTM cell
    {
      const float* pp = gatesP + (size_t)(kt^1) * 262144;
      int j = jt*64 + w*16 + (lane & 15);
#pragma unroll
      for (int ms = 0; ms < 4; ms++)
#pragma unroll
        for (int r = 0; r < 4; r++) {
          int b = ms*16 + (lane>>4)*4 + r;
          acc[ms][r] += __hip_atomic_load(&pp[b*4096 + j], __ATOMIC_RELAXED,
                                          __HIP_MEMORY_SCOPE_AGENT);
        }
    }
    float* sC = (float*)poolA;             // 64*68 floats
    float* sRed = (float*)(poolA + 17408); // 512 floats
    __syncthreads();
    {
      int rr = w*16 + (lane & 15);
#pragma unroll
      for (int ms = 0; ms < 4; ms++)
#pragma unroll
        for (int r = 0; r < 4; r++) {
          int b = ms*16 + (lane>>4)*4 + r;
          sC[b*68 + rr] = acc[ms][r];
        }
    }
    __syncthreads();
    {
      int b = tid & 63;
      float sh = 0.f, sh2 = 0.f;
#pragma unroll
      for (int q = 0; q < 4; q++) {
        int ul = (tid >> 6) + q*4;
        int u = jt*16 + ul;
        float gi_ = sC[b*68 + ul*4 + 0] + b_ih[u]        + b_hh[u];
        float gf  = sC[b*68 + ul*4 + 1] + b_ih[1024 + u] + b_hh[1024 + u];
        float gg  = sC[b*68 + ul*4 + 2] + b_ih[2048 + u] + b_hh[2048 + u];
        float go  = sC[b*68 + ul*4 + 3] + b_ih[3072 + u] + b_hh[3072 + u];
        float cn = sigm(gf)*cbuf[b*1024 + u] + sigm(gi_)*tanhf(gg);
        float hh = sigm(go)*tanhf(cn);
        cbuf[b*1024 + u] = cn;
        hbuf[b*1024 + u] = hh;
        storesplit(hh, inbHn, inbLn, b*1792 + 768 + u);
        sh += hh; sh2 += hh*hh;
      }
      sRed[(tid>>6)*64 + b] = sh;
      sRed[256 + (tid>>6)*64 + b] = sh2;
    }
    __syncthreads();
    if (tid < 64) {
      float s0 = sRed[tid]+sRed[64+tid]+sRed[128+tid]+sRed[192+tid];
      float s1 = sRed[256+tid]+sRed[320+tid]+sRed[384+tid]+sRed[448+tid];
      hstat[(tid*64 + jt)*2]     = s0;
      hstat[(tid*64 + jt)*2 + 1] = s1;
    }
  } else if (bid < 192) {    // qkv for b=bid-128: C[128m][192j], K=64 (split)
    if (t >= 256) return;
    int b = bid - 128;
    const short* Ah = membH + (size_t)b * 8192;
    const short* Al = membL + (size_t)b * 8192;
    int ao = (w*32 + (lane & 15)) * 64 + (lane >> 4) * 8;
    s8v ah00 = *(const s8v*)(Ah + ao);
    s8v ah01 = *(const s8v*)(Ah + ao + 32);
    s8v ah10 = *(const s8v*)(Ah + ao + 16*64);
    s8v ah11 = *(const s8v*)(Ah + ao + 16*64 + 32);
    s8v al00 = *(const s8v*)(Al + ao);
    s8v al01 = *(const s8v*)(Al + ao + 32);
    s8v al10 = *(const s8v*)(Al + ao + 16*64);
    s8v al11 = *(const s8v*)(Al + ao + 16*64 + 32);
    int bo = (lane & 15) * 64 + (lane >> 4) * 8;
    for (int n = 0; n < 12; n++) {
      s8v bh0 = *(const s8v*)(WqH + bo + n*1024);
      s8v bh1 = *(const s8v*)(WqH + bo + n*1024 + 32);
      s8v bl0 = *(const s8v*)(WqL + bo + n*1024);
      s8v bl1 = *(const s8v*)(WqL + bo + n*1024 + 32);
      f32x4 acc0 = {}, acc1 = {};
      acc0 = __builtin_amdgcn_mfma_f32_16x16x32_bf16(ah00, bh0, acc0, 0,0,0);
      acc0 = __builtin_amdgcn_mfma_f32_16x16x32_bf16(ah01, bh1, acc0, 0,0,0);
      acc0 = __builtin_amdgcn_mfma_f32_16x16x32_bf16(al00, bh0, acc0, 0,0,0);
      acc0 = __builtin_amdgcn_mfma_f32_16x16x32_bf16(al01, bh1, acc0, 0,0,0);
      acc0 = __builtin_amdgcn_mfma_f32_16x16x32_bf16(ah00, bl0, acc0, 0,0,0);
      acc0 = __builtin_amdgcn_mfma_f32_16x16x32_bf16(ah01, bl1, acc0, 0,0,0);
      acc1 = __builtin_amdgcn_mfma_f32_16x16x32_bf16(ah10, bh0, acc1, 0,0,0);
      acc1 = __builtin_amdgcn_mfma_f32_16x16x32_bf16(ah11, bh1, acc1, 0,0,0);
      acc1 = __builtin_amdgcn_mfma_f32_16x16x32_bf16(al10, bh0, acc1, 0,0,0);
      acc1 = __builtin_amdgcn_mfma_f32_16x16x32_bf16(al11, bh1, acc1, 0,0,0);
      acc1 = __builtin_amdgcn_mfma_f32_16x16x32_bf16(ah10, bl0, acc1, 0,0,0);
      acc1 = __builtin_amdgcn_mfma_f32_16x16x32_bf16(ah11, bl1, acc1, 0,0,0);
      int j = n*16 + (lane & 15);
      int ch = j >> 6, jj = j & 63;
      float bv = attn_b[j];
#pragma unroll
      for (int r = 0; r < 4; r++) {
        int m0 = w*32 + (lane>>4)*4 + r;
        qkv[((size_t)(b*3 + ch)*128 + m0)*64 + jj] = acc0[r] + bv;
        qkv[((size_t)(b*3 + ch)*128 + m0 + 16)*64 + jj] = acc1[r] + bv;
      }
    }
  } else {                   // logits for step t-1 (single bf16)
    if (t == 0) return;
    int jt = bid - 192;
    f32x4 acc[4] = {};
    const short* B = Wp16 + (size_t)(jt*64 + w*16) * 1280;
    gemm4<1280, 40>(pob16, B, acc, lane);
    int j = jt*64 + w*16 + (lane & 15);
    float bv = b_proj[j];
#pragma unroll
    for (int ms = 0; ms < 4; ms++)
#pragma unroll
      for (int r = 0; r < 4; r++) {
        int b = ms*16 + (lane>>4)*4 + r;
        outs[((size_t)b*256 + (t-1))*1024 + j] = acc[ms][r] + bv;
      }
  }
}

// ---------- kB: heads partials (52, first) | attn (256, 512 thr) ----------
__global__ __launch_bounds__(512) void kB(
    float* __restrict__ mem, const float* __restrict__ qkv,
    const float* __restrict__ attn_ow, const float* __restrict__ attn_ob,
    const float* __restrict__ l1w, const float* __restrict__ l1b,
    const float* __restrict__ l2w, const float* __restrict__ l2b,
    const float* __restrict__ tn1g, const float* __restrict__ tn1b,
    const float* __restrict__ tn2g, const float* __restrict__ tn2b,
    const float* __restrict__ hbuf, const float* __restrict__ hstat,
    const float* __restrict__ cn_g, const float* __restrict__ cn_b,
    const short* __restrict__ WhH, const short* __restrict__ WhL,
    float* __restrict__ hp)
{
  __shared__ float pool[35200];
  int bid = blockIdx.x, tid = threadIdx.x;
  int lane = tid & 63, wid = tid >> 6;
  if (bid < 52) {
    // ---- heads partial: kt = bid&3 (K quarter 256), jt = bid>>2 (0..12) ----
    int kt = bid & 3, jt = bid >> 2;
    {
      int b2 = tid & 63, part = tid >> 6;   // part 0..7
      float s0 = 0.f, s1 = 0.f;
#pragma unroll 4
      for (int m2 = 0; m2 < 8; m2++) {
        int jt2 = part*8 + m2;
        s0 += hstat[(b2*64 + jt2)*2];
        s1 += hstat[(b2*64 + jt2)*2 + 1];
      }
      pool[part*64 + b2] = s0;
      pool[512 + part*64 + b2] = s1;
    }
    __syncthreads();
    if (tid < 64) {
      float ts = 0.f, tq = 0.f;
#pragma unroll
      for (int p2 = 0; p2 < 8; p2++) {
        ts += pool[p2*64 + tid];
        tq += pool[512 + p2*64 + tid];
      }
      float mu = ts / 1024.f;
      pool[1024+tid] = mu;
      pool[1088+tid] = rsqrtf(tq/1024.f - mu*mu + 1e-5f);
    }
    __syncthreads();
    short* sAH = (short*)&pool[1152];
    short* sAL = sAH + 2560;
    int srow = tid >> 3, scol = (tid & 7) * 4;
    int arow = lane & 15, akk = (lane >> 4) * 8;
    f32x4 acc[4] = {};
    for (int c = 0; c < 8; ++c) {
      __syncthreads();
      {
        float mu = pool[1024 + srow], rsd = pool[1088 + srow];
        int kbase = kt*256 + c*32 + scol;
        const float* hpt = hbuf + srow*1024 + kbase;
#pragma unroll
        for (int i = 0; i < 4; i++) {
          float hnv = (hpt[i] - mu) * rsd * cn_g[kbase + i] + cn_b[kbase + i];
          short hh = f2bf(hnv);
          sAH[srow*40 + scol + i] = hh;
          sAL[srow*40 + scol + i] = f2bf(hnv - bf2f(hh));
        }
      }
      __syncthreads();
      if (wid < 4) {
        size_t bo = (size_t)(jt*64 + wid*16 + arow)*1024 + kt*256 + c*32 + akk;
        s8v bh = *(const s8v*)(WhH + bo);
        s8v bl = *(const s8v*)(WhL + bo);
#pragma unroll
        for (int ms = 0; ms < 4; ++ms) {
          s8v ah = *(const s8v*)&sAH[(arow + ms*16)*40 + akk];
          s8v al = *(const s8v*)&sAL[(arow + ms*16)*40 + akk];
          acc[ms] = __builtin_amdgcn_mfma_f32_16x16x32_bf16(ah, bh, acc[ms], 0,0,0);
          acc[ms] = __builtin_amdgcn_mfma_f32_16x16x32_bf16(al, bh, acc[ms], 0,0,0);
          acc[ms] = __builtin_amdgcn_mfma_f32_16x16x32_bf16(ah, bl, acc[ms], 0,0,0);
        }
      }
    }
    if (wid < 4) {
      int j = jt*64 + wid*16 + (lane & 15);
#pragma unroll
      for (int ms = 0; ms < 4; ms++)
#pragma unroll
        for (int r = 0; r < 4; r++) {
          int b2 = ms*16 + (lane>>4)*4 + r;
          hp[(size_t)kt*53248 + b2*832 + j] = acc[ms][r];
        }
    }
    return;
  }
  // ---- attention, 512 threads, 4-way km split ----
  float* sK  = pool;           // 8704
  float* sV  = pool + 8704;    // 8704
  float* sX  = pool + 17408;   // 2176
  float* sM  = pool + 19584;   // 2176
  float* sO  = pool + 21760;   // 2176
  float* sS  = pool + 23936;   // 10240 (512 x 20)
  float* sRed= pool + 34176;   // 1024
  int bb0 = bid - 52;
  int b = bb0 & 63, mt = bb0 >> 6;
  int m0 = mt * 32;
  const float* qb = qkv + (size_t)b*3*8192;
  for (int i = tid*4; i < 8192; i += 2048) {
    *(float4*)&sK[i] = *(const float4*)&qb[8192 + i];
    *(float4*)&sV[i] = *(const float4*)&qb[16384 + i];
  }
  {
    int i = tid*4;
    int m = i >> 6, s = i & 63;
    *(float4*)&sX[m*68+s] = *(const float4*)&qb[m0*64 + i];
    *(float4*)&sM[m*68+s] = *(const float4*)&mem[(size_t)b*8192 + m0*64 + i];
  }
  __syncthreads();
  int m = tid >> 4, hd = (tid >> 2) & 3, q = tid & 3;
  const float* qp = sX + m*68 + hd*16;
  float4 q0 = *(const float4*)(qp),   q1 = *(const float4*)(qp+4);
  float4 q2 = *(const float4*)(qp+8), q3 = *(const float4*)(qp+12);
  int kmb = q * 32;
  float mx = -1e30f;
#pragma unroll 4
  for (int kk = 0; kk < 32; kk++) {
    const float* kp = sK + (kmb+kk)*64 + hd*16;
    float sc = dot4(q0, *(const float4*)kp)     + dot4(q1, *(const float4*)(kp+4))
             + dot4(q2, *(const float4*)(kp+8)) + dot4(q3, *(const float4*)(kp+12));
    mx = fmaxf(mx, sc * 0.25f);
  }
  float4 o0 = {0,0,0,0}, o1 = {0,0,0,0}, o2 = {0,0,0,0}, o3 = {0,0,0,0};
  float sum = 0.f;
#pragma unroll 4
  for (int kk = 0; kk < 32; kk++) {
    const float* kp = sK + (kmb+kk)*64 + hd*16;
    float sc = dot4(q0, *(const float4*)kp)     + dot4(q1, *(const float4*)(kp+4))
             + dot4(q2, *(const float4*)(kp+8)) + dot4(q3, *(const float4*)(kp+12));
    float e = expf(sc * 0.25f - mx);
    sum += e;
    const float* vp = sV + (kmb+kk)*64 + hd*16;
    float4 v0 = *(const float4*)vp,     v1 = *(const float4*)(vp+4);
    float4 v2 = *(const float4*)(vp+8), v3 = *(const float4*)(vp+12);
    o0.x += e*v0.x; o0.y += e*v0.y; o0.z += e*v0.z; o0.w += e*v0.w;
    o1.x += e*v1.x; o1.y += e*v1.y; o1.z += e*v1.z; o1.w += e*v1.w;
    o2.x += e*v2.x; o2.y += e*v2.y; o2.z += e*v2.z; o2.w += e*v2.w;
    o3.x += e*v3.x; o3.y += e*v3.y; o3.z += e*v3.z; o3.w += e*v3.w;
  }
  {
    float* pp = sS + tid*20;
    *(float4*)&pp[0]  = o0; *(float4*)&pp[4]  = o1;
    *(float4*)&pp[8]  = o2; *(float4*)&pp[12] = o3;
    sRed[tid] = mx; sRed[512+tid] = sum;
  }
  __syncthreads();
  if (q == 0) {
    float m1 = sRed[tid+1], m2 = sRed[tid+2], m3 = sRed[tid+3];
    float M = fmaxf(fmaxf(mx, m1), fmaxf(m2, m3));
    float e0 = expf(mx - M), e1 = expf(m1 - M), e2 = expf(m2 - M), e3 = expf(m3 - M);
    float inv = 1.0f / (sum*e0 + sRed[512+tid+1]*e1 + sRed[512+tid+2]*e2
                        + sRed[512+tid+3]*e3);
    const float* p1 = sS + (tid+1)*20;
    const float* p2 = sS + (tid+2)*20;
    const float* p3 = sS + (tid+3)*20;
    float oo[16];
    *(float4*)&oo[0] = o0; *(float4*)&oo[4] = o1;
    *(float4*)&oo[8] = o2; *(float4*)&oo[12] = o3;
    float* op = sO + m*68 + hd*16;
#pragma unroll
    for (int d = 0; d < 16; d++)
      op[d] = (oo[d]*e0 + p1[d]*e1 + p2[d]*e2 + p3[d]*e3) * inv;
  }
  __syncthreads();
  for (int idx = tid; idx < 4096; idx += 512) {
    int j = idx >> 6, s = idx & 63;
    sS[j*68 + s] = attn_ow[idx];
  }
  __syncthreads();
  {
    int mm = tid >> 4, jset = tid & 15;
    float4 orow[16];
#pragma unroll
    for (int r = 0; r < 16; r++) orow[r] = *(const float4*)&sO[mm*68 + r*4];
#pragma unroll
    for (int i = 0; i < 4; i++) {
      int j = jset + 16*i;
      const float* wr = sS + j*68;
      float acc = attn_ob[j];
#pragma unroll
      for (int r = 0; r < 16; r++) acc += dot4(orow[r], *(const float4*)&wr[r*4]);
      sM[mm*68 + j] += acc;
    }
  }
  __syncthreads();
  for (int r = wid; r < 32; r += 8) {
    float v = sM[r*68 + lane];
    float ssum = wsum(v), ssq = wsum(v*v);
    float mu = ssum*(1.f/64), var = ssq*(1.f/64) - mu*mu;
    sX[r*68+lane] = (v - mu)*rsqrtf(var+1e-5f)*tn1g[lane] + tn1b[lane];
  }
  for (int idx = tid; idx < 8192; idx += 512) {
    int f = idx >> 6, s = idx & 63;
    sK[f*68 + s] = l1w[idx];
  }
  for (int idx = tid; idx < 8192; idx += 512) {
    int j = idx >> 7, s = idx & 127;
    sV[j*132 + s] = l2w[idx];
  }
  __syncthreads();
  {
    int mm = tid >> 4, fs = tid & 15;
    float4 xr[16];
#pragma unroll
    for (int r = 0; r < 16; r++) xr[r] = *(const float4*)&sX[mm*68 + r*4];
#pragma unroll 4
    for (int i = 0; i < 8; i++) {
      int f = fs + 16*i;
      const float* wr = sK + f*68;
      float acc = l1b[f];
#pragma unroll
      for (int r = 0; r < 16; r++) acc += dot4(xr[r], *(const float4*)&wr[r*4]);
      sS[mm*132 + f] = 0.5f*acc*(1.0f + erff(acc*0.70710678118654752f));
    }
  }
  __syncthreads();
  {
    int mm = tid >> 4, jset = tid & 15;
    float acc6[4];
#pragma unroll
    for (int i = 0; i < 4; i++) acc6[i] = sX[mm*68 + jset + 16*i] + l2b[jset + 16*i];
#pragma unroll
    for (int h = 0; h < 2; h++) {
      float4 fr[16];
#pragma unroll
      for (int r = 0; r < 16; r++) fr[r] = *(const float4*)&sS[mm*132 + h*64 + r*4];
#pragma unroll
      for (int i = 0; i < 4; i++) {
        int j = jset + 16*i;
        const float* wr = sV + j*132 + h*64;
        float a = 0.f;
#pragma unroll
        for (int r = 0; r < 16; r++) a += dot4(fr[r], *(const float4*)&wr[r*4]);
        acc6[i] += a;
      }
    }
#pragma unroll
    for (int i = 0; i < 4; i++) sO[mm*68 + jset + 16*i] = acc6[i];
  }
  __syncthreads();
  for (int r = wid; r < 32; r += 8) {
    float v = sO[r*68 + lane];
    float ssum = wsum(v), ssq = wsum(v*v);
    float mu = ssum*(1.f/64), var = ssq*(1.f/64) - mu*mu;
    mem[(size_t)b*8192 + (m0+r)*64 + lane] =
        (v - mu)*rsqrtf(var+1e-5f)*tn2g[lane] + tn2b[lane];
  }
}

// ---------- kC: heads finalize + addressing + output LN + next xin (512 thr) ----------
__global__ __launch_bounds__(512) void kC(
    float* __restrict__ mem, short* __restrict__ membH, short* __restrict__ membL,
    const float* __restrict__ hp, const float* __restrict__ hstat,
    const float* __restrict__ hbuf,
    const float* __restrict__ b_rk, const float* __restrict__ b_wk,
    const float* __restrict__ b_ev, const float* __restrict__ b_ws,
    const float* __restrict__ rkn_g, const float* __restrict__ rkn_b,
    const float* __restrict__ wkn_g, const float* __restrict__ wkn_b,
    const float* __restrict__ cn_g, const float* __restrict__ cn_b,
    const float* __restrict__ mng, const float* __restrict__ mnb,
    const float* __restrict__ pog, const float* __restrict__ pob,
    const float* __restrict__ x_emb, const float* __restrict__ in_g,
    const float* __restrict__ in_b,
    short* __restrict__ inbHn, short* __restrict__ inbLn,
    short* __restrict__ pob16, int tnext)
{
  __shared__ float P[20960];
  float* sMT  = P;            // 8192
  float* sMN  = P + 8192;     // 8320
  float* sHn  = P + 16512;    // 1024
  float* sRk  = P + 17536;    // 256
  float* sWk  = P + 17792;    // 256
  float* sEv  = P + 18048;    // 256
  float* sWs  = P + 18304;    // 4
  float* sRw  = P + 18308;    // 512
  float* sWw  = P + 18820;    // 512
  float* sRc  = P + 19332;    // 256
  float* sRcP = P + 19588;    // 512
  float* rs   = P + 20100;    // 8
  float* rq   = P + 20108;    // 8
  float* sHst = P + 20116;    // 2
  int b = blockIdx.x, tid = threadIdx.x, lane = tid & 63, wv = tid >> 6;
  // stage mem + hn stats
  for (int i = tid*4; i < 8192; i += 2048)
    *(float4*)&sMT[i] = *(const float4*)&mem[(size_t)b*8192 + i];
  if (wv == 0) {
    float v0 = hstat[(b*64 + lane)*2], v1 = hstat[(b*64 + lane)*2 + 1];
    float s0 = wsum(v0), s1 = wsum(v1);
    if (lane == 0) {
      float mu = s0 / 1024.f;
      sHst[0] = mu;
      sHst[1] = rsqrtf(s1/1024.f - mu*mu + 1e-5f);
    }
  }
  __syncthreads();
  // hn from hbuf + stats
  {
    float mu = sHst[0], rstd = sHst[1];
    for (int u = tid; u < 1024; u += 512)
      sHn[u] = (hbuf[b*1024 + u] - mu)*rstd*cn_g[u] + cn_b[u];
  }
  // heads finalize: 4 partials + bias -> key LN / sigmoids into LDS
  {
    const float* h0 = hp + (size_t)b*832;
    const float* h1 = hp + 53248 + (size_t)b*832;
    const float* h2 = hp + 2*53248 + (size_t)b*832;
    const float* h3 = hp + 3*53248 + (size_t)b*832;
    if (wv < 4) {
      int idx = wv*64 + lane;    // 0..255
      float v = h0[idx] + h1[idx] + h2[idx] + h3[idx] + b_rk[idx];
      float ssum = wsum(v), ssq = wsum(v*v);
      float mu = ssum*(1.f/64), var = ssq*(1.f/64) - mu*mu;
      sRk[idx] = (v - mu)*rsqrtf(var+1e-5f)*rkn_g[lane] + rkn_b[lane];
    } else {
      int idx = (wv-4)*64 + lane;
      float v = h0[256+idx] + h1[256+idx] + h2[256+idx] + h3[256+idx] + b_wk[idx];
      float ssum = wsum(v), ssq = wsum(v*v);
      float mu = ssum*(1.f/64), var = ssq*(1.f/64) - mu*mu;
      sWk[idx] = (v - mu)*rsqrtf(var+1e-5f)*wkn_g[lane] + wkn_b[lane];
    }
    if (tid < 256)
      sEv[tid] = sigm(h0[512+tid] + h1[512+tid] + h2[512+tid] + h3[512+tid] + b_ev[tid]);
    if (tid >= 256 && tid < 260) {
      int n = tid - 256;
      sWs[n] = sigm(h0[768+n] + h1[768+n] + h2[768+n] + h3[768+n] + b_ws[n]);
    }
  }
  // mem_n LN (8 waves)
  for (int r = wv; r < 128; r += 8) {
    float v = sMT[r*64 + lane];
    float ssum = wsum(v), ssq = wsum(v*v);
    float mu = ssum*(1.f/64), var = ssq*(1.f/64) - mu*mu;
    sMN[r*65 + lane] = (v - mu)*rsqrtf(var+1e-5f)*mng[lane] + mnb[lane];
  }
  __syncthreads();
  // scores (2 x 512)
#pragma unroll
  for (int q = 0; q < 2; q++) {
    int idx = tid + q*512;
    int which = idx >> 9;
    int n = (idx >> 7) & 3, m = idx & 127;
    const float* key = (which ? sWk : sRk) + n*64;
    const float* mr = sMN + m*65;
    float acc = 0.f;
#pragma unroll 8
    for (int k = 0; k < 64; k++) acc += key[k]*mr[k];
    (which ? sWw : sRw)[n*128 + m] = acc;
  }
  __syncthreads();
  // softmax (8 rows, one per wave)
  {
    float* row = (wv < 4) ? (sRw + wv*128) : (sWw + (wv-4)*128);
    float a0 = row[lane], a1 = row[lane+64];
    float mx = fmaxf(a0, a1);
#pragma unroll
    for (int o = 32; o > 0; o >>= 1) mx = fmaxf(mx, __shfl_xor(mx, o, 64));
    float e0 = expf(a0 - mx), e1 = expf(a1 - mx);
    float inv = 1.0f / wsum(e0 + e1);
    row[lane] = e0*inv; row[lane+64] = e1*inv;
  }
  __syncthreads();
  // rc partials (2 halves)
  {
    int idx = tid & 255, h2 = tid >> 8;
    int n = idx >> 6, s2 = idx & 63;
    float acc = 0.f;
    for (int mm = h2*64; mm < h2*64 + 64; mm++) acc += sRw[n*128 + mm] * sMT[mm*64 + s2];
    sRcP[tid] = acc;
  }
  __syncthreads();
  if (tid < 256) sRc[tid] = sRcP[tid] + sRcP[256 + tid];
  // mem update (in place) + bf16 split for next qkv
  for (int idx = tid; idx < 8192; idx += 512) {
    int mm = idx >> 6, s2 = idx & 63;
    float er = 0.f, ad = 0.f;
#pragma unroll
    for (int n = 0; n < 4; n++) {
      float w = sWw[n*128 + mm];
      er += w * sEv[n*64 + s2];
      ad += w * sWs[n] * sWk[n*64 + s2];
    }
    float val = sMT[idx]*(1.0f - er) + ad;
    mem[(size_t)b*8192 + idx] = val;
    storesplit(val, membH, membL, (size_t)b*8192 + idx);
  }
  __syncthreads();
  // output LN over 1280 = [hn | rc]
  {
    float v5[3]; float s = 0.f, sq = 0.f;
#pragma unroll
    for (int i = 0; i < 3; i++) {
      int k = tid + i*512;
      float v = 0.f;
      if (k < 1280) v = (k < 1024) ? sHn[k] : sRc[k-1024];
      v5[i] = v; s += v; sq += v*v;
    }
    s = wsum(s); sq = wsum(sq);
    if (lane == 0) { rs[wv] = s; rq[wv] = sq; }
    __syncthreads();
    float ts = 0.f, tq = 0.f;
#pragma unroll
    for (int p = 0; p < 8; p++) { ts += rs[p]; tq += rq[p]; }
    float mu = ts/1280.f, var = tq/1280.f - mu*mu;
    float rstd = rsqrtf(var + 1e-5f);
#pragma unroll
    for (int i = 0; i < 3; i++) {
      int k = tid + i*512;
      if (k < 1280) pob16[b*1280 + k] = f2bf((v5[i] - mu)*rstd*pog[k] + pob[k]);
    }
  }
  // next-step xin
  if (tnext < 256) {
    __syncthreads();
    float v3[2]; float s2 = 0.f, q2 = 0.f;
#pragma unroll
    for (int i = 0; i < 2; i++) {
      int k = tid + i*512;
      float v = 0.f;
      if (k < 768) v = (k < 512) ? x_emb[((size_t)b*256 + tnext)*512 + k] : sRc[k-512];
      v3[i] = v; s2 += v; q2 += v*v;
    }
    s2 = wsum(s2); q2 = wsum(q2);
    if (lane == 0) { rs[wv] = s2; rq[wv] = q2; }
    __syncthreads();
    float ts = 0.f, tq = 0.f;
#pragma unroll
    for (int p = 0; p < 8; p++) { ts += rs[p]; tq += rq[p]; }
    float mu = ts/768.f, var = tq/768.f - mu*mu;
    float rstd = rsqrtf(var + 1e-5f);
#pragma unroll
    for (int i = 0; i < 2; i++) {
      int k = tid + i*512;
      if (k < 768)
        storesplit((v3[i] - mu)*rstd*in_g[k] + in_b[k], inbHn, inbLn, b*1792 + k);
    }
  }
}

// ---------- final copy ----------
__global__ void k_final(const float* __restrict__ mem, const float* __restrict__ hbuf,
                        const float* __restrict__ cbuf, float* __restrict__ out)
{
  int i = blockIdx.x * 256 + threadIdx.x;
  if (i < 524288) out[16777216 + i] = mem[i];
  if (i < 65536) {
    out[17301504 + i] = hbuf[i];
    out[17367040 + i] = cbuf[i];
  }
}

extern "C" void kernel_launch(void* const* d_in, const int* in_sizes, int n_in,
                              void* d_out, int out_size, void* d_ws, size_t ws_size,
                              hipStream_t stream) {
  const float* x_emb  = (const float*)d_in[0];
  const float* in_g   = (const float*)d_in[1];
  const float* in_b   = (const float*)d_in[2];
  const float* W_ih   = (const float*)d_in[3];
  const float* W_hh   = (const float*)d_in[4];
  const float* b_ih   = (const float*)d_in[5];
  const float* b_hh   = (const float*)d_in[6];
  const float* cn_g   = (const float*)d_in[7];
  const float* cn_b   = (const float*)d_in[8];
  const float* W_rk   = (const float*)d_in[9];
  const float* b_rk   = (const float*)d_in[10];
  const float* W_wk   = (const float*)d_in[11];
  const float* b_wk   = (const float*)d_in[12];
  const float* W_ws   = (const float*)d_in[13];
  const float* b_ws   = (const float*)d_in[14];
  const float* W_ev   = (const float*)d_in[15];
  const float* b_ev   = (const float*)d_in[16];
  const float* attn_w = (const float*)d_in[17];
  const float* attn_b = (const float*)d_in[18];
  const float* attn_ow= (const float*)d_in[19];
  const float* attn_ob= (const float*)d_in[20];
  const float* l1_w   = (const float*)d_in[21];
  const float* l1_b   = (const float*)d_in[22];
  const float* l2_w   = (const float*)d_in[23];
  const float* l2_b   = (const float*)d_in[24];
  const float* tn1_g  = (const float*)d_in[25];
  const float* tn1_b  = (const float*)d_in[26];
  const float* tn2_g  = (const float*)d_in[27];
  const float* tn2_b  = (const float*)d_in[28];
  const float* rkn_g  = (const float*)d_in[29];
  const float* rkn_b  = (const float*)d_in[30];
  const float* wkn_g  = (const float*)d_in[31];
  const float* wkn_b  = (const float*)d_in[32];
  const float* mn_g   = (const float*)d_in[33];
  const float* mn_b   = (const float*)d_in[34];
  const float* po_g   = (const float*)d_in[35];
  const float* po_b   = (const float*)d_in[36];
  const float* W_proj = (const float*)d_in[37];
  const float* b_proj = (const float*)d_in[38];

  float* ws = (float*)d_ws;
  float* mem    = ws;                 // 524288
  float* cbuf   = ws + 524288;        // 65536
  float* hbuf   = ws + 589824;        // 65536
  float* gatesP = ws + 655360;        // 524288 (2 partials)
  float* hp     = ws + 1179648;       // 212992 (4 x 64 x 832)
  float* hstat  = ws + 1392640;       // 8192
  unsigned* tick = (unsigned*)(ws + 1400832); // 64
  float* qkvb   = ws + 1400896;       // 1572864 -> end 2973760 floats
  short* sb     = (short*)(ws + 2973760);
  short* inbH0 = sb;                  // 114688
  short* inbL0 = sb + 114688;         // 114688
  short* inbH1 = sb + 229376;         // 114688
  short* inbL1 = sb + 344064;         // 114688
  short* membH = sb + 458752;         // 524288
  short* membL = sb + 983040;         // 524288
  short* pob16 = sb + 1507328;        // 81920
  short* WgH   = sb + 1589248;        // 7340032
  short* WgL   = sb + 8929280;        // 7340032
  short* WhH   = sb + 16269312;       // 851968
  short* WhL   = sb + 17121280;       // 851968
  short* WqH   = sb + 17973248;       // 12288
  short* WqL   = sb + 17985536;       // 12288
  short* Wp16  = sb + 17997824;       // 1310720 -> end 19308544 shorts

  hipMemsetAsync(ws, 0, 655360 * sizeof(float), stream);      // mem, cbuf, hbuf
  hipMemsetAsync(tick, 0, 256, stream);
  hipMemsetAsync(sb, 0, 1507328 * sizeof(short), stream);     // inb x2, memb

  kprep_g<<<dim3(7, 4096), 256, 0, stream>>>(W_ih, W_hh, WgH, WgL);
  kprep_p<<<dim3(5, 1024), 256, 0, stream>>>(W_proj, Wp16);
  kprep_h<<<dim3(4, 832), 256, 0, stream>>>(W_rk, W_wk, W_ev, W_ws, WhH, WhL);
  kprep_q<<<dim3(192), 64, 0, stream>>>(attn_w, WqH, WqL);
  k_prep0<<<64, 256, 0, stream>>>(x_emb, in_g, in_b, inbH0, inbL0);

  float* outs = (float*)d_out;
  short* bufsH[2] = {inbH0, inbH1};
  short* bufsL[2] = {inbL0, inbL1};
  for (int t = 0; t < 256; t++) {
    kA<<<208, 256, 0, stream>>>(bufsH[t&1], bufsL[t&1], bufsH[(t+1)&1], bufsL[(t+1)&1],
                                WgH, WgL, b_ih, b_hh, cbuf, hbuf, hstat, gatesP, tick,
                                membH, membL, WqH, WqL, attn_b,
                                pob16, Wp16, b_proj, qkvb, outs, t);
    kB<<<308, 512, 0, stream>>>(mem, qkvb, attn_ow, attn_ob,
                                l1_w, l1_b, l2_w, l2_b,
                                tn1_g, tn1_b, tn2_g, tn2_b,
                                hbuf, hstat, cn_g, cn_b, WhH, WhL, hp);
    kC<<<64, 512, 0, stream>>>(mem, membH, membL, hp, hstat, hbuf,
                               b_rk, b_wk, b_ev, b_ws,
                               rkn_g, rkn_b, wkn_g, wkn_b, cn_g, cn_b,
                               mn_g, mn_b, po_g, po_b,
                               x_emb, in_g, in_b,
                               bufsH[(t+1)&1], bufsL[(t+1)&1], pob16, t+1);
  }
  // last-step logits
  kA<<<208, 256, 0, stream>>>(bufsH[0], bufsL[0], bufsH[1], bufsL[1],
                              WgH, WgL, b_ih, b_hh, cbuf, hbuf, hstat, gatesP, tick,
                              membH, membL, WqH, WqL, attn_b,
                              pob16, Wp16, b_proj, qkvb, outs, 256);
  k_final<<<2048, 256, 0, stream>>>(mem, hbuf, cbuf, (float*)d_out);
}